// Round 2
// baseline (717.794 us; speedup 1.0000x reference)
//
#include <hip/hip_runtime.h>
#include <math.h>

// Problem: J=25, F=38400, C=128, B=128 (dims derived at launch).
// x (J,F,C) fp32; idx sorted; out (J,B,C) fp32.
//
// R4: chunked-over-j L3-residency restructure.
//   - Sweep j in 3 chunks (9,8,8 j's = 177/157/157 MB, each < 256 MB L3).
//   - Per chunk: pass-1 (mean+gc fused, CACHING loads -> x lands in L3),
//     then pass-2 (gate_scatter, NT loads -> reads x from L3, evict-first).
//   - HBM traffic for x: 983 MB -> ~500 MB; pass-2 runs at L3 BW.
//   - gc fused into pass-1 epilogue (block already has mean row in LDS);
//     mean buffer round-trip removed.
// Prediction: dur 690 -> 440-590 if kernel/HBM-contention dominates;
// 640-670 if harness fill traffic dominates serially.

typedef float f4v __attribute__((ext_vector_type(4)));

__global__ void seg_bounds_kernel(const int* __restrict__ idx, int F, int B,
                                  int* __restrict__ seg) {
    int b = blockIdx.x * blockDim.x + threadIdx.x;
    if (b > B) return;
    int lo = 0, hi = F;
    while (lo < hi) {
        int mid = (lo + hi) >> 1;
        if (idx[mid] < b) lo = mid + 1; else hi = mid;
    }
    seg[b] = lo;
}

// Pass 1, fused: per-(j,b) segment mean + gc row = tanh(mean @ W).
// One block per (j,b) within chunk. 256 threads = 8 frame-rows x 32 lanes.
// CACHING loads (no NT): x must allocate in L3 for pass-2 reuse.
__global__ void __launch_bounds__(256) mean_gc_kernel(
    const float* __restrict__ x, const int* __restrict__ seg,
    const float* __restrict__ W, int F, int B, int jbase,
    float* __restrict__ gc) {
    const int bid = blockIdx.x;
    const int j = jbase + bid / B, b = bid - (bid / B) * B;
    const int f0 = seg[b], f1 = seg[b + 1];
    const int tid = threadIdx.x;
    const int lane32 = tid & 31;
    const int row = tid >> 5;

    const f4v* __restrict__ xp =
        (const f4v*)(x + (size_t)j * F * 128) + lane32;
    f4v a0 = {0.f, 0.f, 0.f, 0.f};
    f4v a1 = {0.f, 0.f, 0.f, 0.f};
    f4v a2 = {0.f, 0.f, 0.f, 0.f};
    f4v a3 = {0.f, 0.f, 0.f, 0.f};

    int f = f0 + row;
    const f4v* p = xp + (size_t)f * 32;
    for (; f + 56 < f1; f += 64, p += 2048) {
        f4v v0 = p[0];
        f4v v1 = p[256];
        f4v v2 = p[512];
        f4v v3 = p[768];
        f4v v4 = p[1024];
        f4v v5 = p[1280];
        f4v v6 = p[1536];
        f4v v7 = p[1792];
        a0 += v0; a1 += v1; a2 += v2; a3 += v3;
        a0 += v4; a1 += v5; a2 += v6; a3 += v7;
    }
    for (; f < f1; f += 8, p += 256) a0 += p[0];
    a0 += a1; a2 += a3; a0 += a2;

    __shared__ f4v s[256];
    __shared__ float srow[128];
    s[tid] = a0;
    __syncthreads();
#pragma unroll
    for (int stride = 128; stride >= 32; stride >>= 1) {
        if (tid < stride) {
            f4v m = s[tid] + s[tid + stride];
            s[tid] = m;
        }
        __syncthreads();
    }
    if (tid < 32) {
        float inv = 1.0f / fmaxf((float)(f1 - f0), 1.0f);
        f4v m = s[tid] * inv;
        srow[tid * 4 + 0] = m[0];
        srow[tid * 4 + 1] = m[1];
        srow[tid * 4 + 2] = m[2];
        srow[tid * 4 + 3] = m[3];
    }
    __syncthreads();
    // gc[t] = tanh(sum_k srow[k] * W[k,t]); W is L2-resident (64 KB).
    if (tid < 128) {
        float acc = 0.f;
#pragma unroll 8
        for (int k = 0; k < 128; ++k) acc = fmaf(srow[k], W[k * 128 + tid], acc);
        gc[((size_t)j * B + b) * 128 + tid] = tanhf(acc);
    }
}

__device__ __forceinline__ float dot4(const f4v a, const f4v b) {
    return a[0] * b[0] + a[1] * b[1] + a[2] * b[2] + a[3] * b[3];
}

// Pass 2: gate + scatter-mean. NT loads: x comes from L3 (placed by pass-1),
// evict-first frees L3 for the next chunk.
__global__ void __launch_bounds__(256) gate_scatter_kernel(
    const float* __restrict__ x, const float* __restrict__ gc,
    const int* __restrict__ seg, int F, int B, int jbase,
    float* __restrict__ out) {
    const int bid = blockIdx.x;
    const int j = jbase + bid / B, b = bid - (bid / B) * B;
    const int f0 = seg[b], f1 = seg[b + 1];
    const int tid = threadIdx.x;
    const int lane32 = tid & 31;
    const int row = tid >> 5;

    const f4v* __restrict__ xp =
        (const f4v*)(x + (size_t)j * F * 128) + lane32;
    const f4v g = ((const f4v*)(gc + ((size_t)j * B + b) * 128))[lane32];

    f4v a0 = {0.f, 0.f, 0.f, 0.f};
    f4v a1 = {0.f, 0.f, 0.f, 0.f};

    int f = f0 + row;
    const f4v* p = xp + (size_t)f * 32;
    for (; f + 24 < f1; f += 32, p += 1024) {
        f4v v0 = __builtin_nontemporal_load(p);
        f4v v1 = __builtin_nontemporal_load(p + 256);
        f4v v2 = __builtin_nontemporal_load(p + 512);
        f4v v3 = __builtin_nontemporal_load(p + 768);
        float p0 = dot4(v0, g), p1 = dot4(v1, g),
              p2 = dot4(v2, g), p3 = dot4(v3, g);
#pragma unroll
        for (int m = 16; m >= 1; m >>= 1) {
            p0 += __shfl_xor(p0, m, 64);
            p1 += __shfl_xor(p1, m, 64);
            p2 += __shfl_xor(p2, m, 64);
            p3 += __shfl_xor(p3, m, 64);
        }
        float g0 = 1.0f / (1.0f + __expf(-p0));
        float g1 = 1.0f / (1.0f + __expf(-p1));
        float g2 = 1.0f / (1.0f + __expf(-p2));
        float g3 = 1.0f / (1.0f + __expf(-p3));
        a0 += g0 * v0 + g2 * v2;
        a1 += g1 * v1 + g3 * v3;
    }
    for (; f < f1; f += 8, p += 256) {
        f4v v = __builtin_nontemporal_load(p);
        float pp = dot4(v, g);
#pragma unroll
        for (int m = 16; m >= 1; m >>= 1) pp += __shfl_xor(pp, m, 64);
        float gg = 1.0f / (1.0f + __expf(-pp));
        a0 += gg * v;
    }
    a0 += a1;

    __shared__ f4v s[256];
    s[tid] = a0;
    __syncthreads();
#pragma unroll
    for (int stride = 128; stride >= 32; stride >>= 1) {
        if (tid < stride) {
            f4v m = s[tid] + s[tid + stride];
            s[tid] = m;
        }
        __syncthreads();
    }
    if (tid < 32) {
        float inv = 1.0f / fmaxf((float)(f1 - f0), 1.0f);
        f4v m = s[tid];
        ((f4v*)(out + ((size_t)j * B + b) * 128))[tid] = m * inv;
    }
}

extern "C" void kernel_launch(void* const* d_in, const int* in_sizes, int n_in,
                              void* d_out, int out_size, void* d_ws, size_t ws_size,
                              hipStream_t stream) {
    const float* x  = (const float*)d_in[0];
    const int* idx  = (const int*)d_in[1];
    const float* W  = (const float*)d_in[3];
    float* out      = (float*)d_out;

    const int F = in_sizes[1];
    int C = 1;
    while ((long long)C * C < (long long)in_sizes[3]) ++C;   // 128
    const int J = in_sizes[0] / (F * C);                     // 25
    const int B = out_size / (J * C);                        // 128

    char* ws = (char*)d_ws;
    int* seg = (int*)ws;
    size_t off = (((size_t)(B + 1) * sizeof(int)) + 255) & ~(size_t)255;
    float* gcb = (float*)(ws + off);

    seg_bounds_kernel<<<(B + 1 + 255) / 256, 256, 0, stream>>>(idx, F, B, seg);

    // Chunked j-sweep: chunk x-bytes must fit L3 (256 MB).
    // J=25 -> chunks of 9,8,8 (177/157/157 MB).
    const int NCH = 3;
    int jdone = 0;
    for (int c = 0; c < NCH && jdone < J; ++c) {
        int jcnt = (J - jdone + (NCH - 1 - c)) / (NCH - c);
        mean_gc_kernel<<<jcnt * B, 256, 0, stream>>>(x, seg, W, F, B, jdone, gcb);
        gate_scatter_kernel<<<jcnt * B, 256, 0, stream>>>(x, gcb, seg, F, B, jdone, out);
        jdone += jcnt;
    }
}

// Round 3
// 685.611 us; speedup vs baseline: 1.0469x; 1.0469x over previous
//
#include <hip/hip_runtime.h>
#include <math.h>

// Problem: J=25, F=38400, C=128, B=128 (dims derived at launch).
// x (J,F,C) fp32; idx sorted; out (J,B,C) fp32.
//
// R5: best-of breed. R4's L3-chunking FALSIFIED (fills thrash L3; +27 us).
// Structure = R3 (2 full-sweep streaming passes, NT loads everywhere,
// deep MLP) + R4's gc-fusion (one fewer launch, no mean round-trip).
// New: gate_scatter unroll x4 -> x8 (8 outstanding NT loads, 8 independent
// shuffle-reduce chains) -- under HBM contention with concurrent harness
// fills, effective latency rises, so deeper MLP sustains throughput.
// Prediction: 655-685 if MLP lever real; 685-700 => combined-traffic
// roofline (ours 983 MB + fills 3.93 GB at ~6.9 TB/s), declare next round.

typedef float f4v __attribute__((ext_vector_type(4)));

__global__ void seg_bounds_kernel(const int* __restrict__ idx, int F, int B,
                                  int* __restrict__ seg) {
    int b = blockIdx.x * blockDim.x + threadIdx.x;
    if (b > B) return;
    int lo = 0, hi = F;
    while (lo < hi) {
        int mid = (lo + hi) >> 1;
        if (idx[mid] < b) lo = mid + 1; else hi = mid;
    }
    seg[b] = lo;
}

// Pass 1, fused: per-(j,b) segment mean + gc row = tanh(mean @ W).
// One block per (j,b). 256 threads = 8 frame-rows x 32 lanes, float4/lane.
// NT loads (evict-first): x will NOT be re-read from cache (fills thrash L3).
__global__ void __launch_bounds__(256) mean_gc_kernel(
    const float* __restrict__ x, const int* __restrict__ seg,
    const float* __restrict__ W, int F, int B,
    float* __restrict__ gc) {
    const int bid = blockIdx.x;
    const int j = bid / B, b = bid - (bid / B) * B;
    const int f0 = seg[b], f1 = seg[b + 1];
    const int tid = threadIdx.x;
    const int lane32 = tid & 31;
    const int row = tid >> 5;

    const f4v* __restrict__ xp =
        (const f4v*)(x + (size_t)j * F * 128) + lane32;
    f4v a0 = {0.f, 0.f, 0.f, 0.f};
    f4v a1 = {0.f, 0.f, 0.f, 0.f};
    f4v a2 = {0.f, 0.f, 0.f, 0.f};
    f4v a3 = {0.f, 0.f, 0.f, 0.f};

    int f = f0 + row;
    const f4v* p = xp + (size_t)f * 32;
    for (; f + 56 < f1; f += 64, p += 2048) {
        f4v v0 = __builtin_nontemporal_load(p);
        f4v v1 = __builtin_nontemporal_load(p + 256);
        f4v v2 = __builtin_nontemporal_load(p + 512);
        f4v v3 = __builtin_nontemporal_load(p + 768);
        f4v v4 = __builtin_nontemporal_load(p + 1024);
        f4v v5 = __builtin_nontemporal_load(p + 1280);
        f4v v6 = __builtin_nontemporal_load(p + 1536);
        f4v v7 = __builtin_nontemporal_load(p + 1792);
        a0 += v0; a1 += v1; a2 += v2; a3 += v3;
        a0 += v4; a1 += v5; a2 += v6; a3 += v7;
    }
    for (; f < f1; f += 8, p += 256) a0 += __builtin_nontemporal_load(p);
    a0 += a1; a2 += a3; a0 += a2;

    __shared__ f4v s[256];
    __shared__ float srow[128];
    s[tid] = a0;
    __syncthreads();
#pragma unroll
    for (int stride = 128; stride >= 32; stride >>= 1) {
        if (tid < stride) {
            f4v m = s[tid] + s[tid + stride];
            s[tid] = m;
        }
        __syncthreads();
    }
    if (tid < 32) {
        float inv = 1.0f / fmaxf((float)(f1 - f0), 1.0f);
        f4v m = s[tid] * inv;
        srow[tid * 4 + 0] = m[0];
        srow[tid * 4 + 1] = m[1];
        srow[tid * 4 + 2] = m[2];
        srow[tid * 4 + 3] = m[3];
    }
    __syncthreads();
    // gc[t] = tanh(sum_k srow[k] * W[k,t]); W (64 KB) is L2-resident.
    if (tid < 128) {
        float acc = 0.f;
#pragma unroll 8
        for (int k = 0; k < 128; ++k) acc = fmaf(srow[k], W[k * 128 + tid], acc);
        gc[((size_t)j * B + b) * 128 + tid] = tanhf(acc);
    }
}

__device__ __forceinline__ float dot4(const f4v a, const f4v b) {
    return a[0] * b[0] + a[1] * b[1] + a[2] * b[2] + a[3] * b[3];
}

// Pass 2: gate + scatter-mean. Unroll x8: 8 outstanding NT loads, 8
// independent shuffle-reduce chains. xor masks <=16 stay within each
// 32-lane half-wave, so divergent row-exit at segment tails is safe.
__global__ void __launch_bounds__(256) gate_scatter_kernel(
    const float* __restrict__ x, const float* __restrict__ gc,
    const int* __restrict__ seg, int F, int B,
    float* __restrict__ out) {
    const int bid = blockIdx.x;
    const int j = bid / B, b = bid - (bid / B) * B;
    const int f0 = seg[b], f1 = seg[b + 1];
    const int tid = threadIdx.x;
    const int lane32 = tid & 31;
    const int row = tid >> 5;

    const f4v* __restrict__ xp =
        (const f4v*)(x + (size_t)j * F * 128) + lane32;
    const f4v g = ((const f4v*)(gc + ((size_t)j * B + b) * 128))[lane32];

    f4v a0 = {0.f, 0.f, 0.f, 0.f};
    f4v a1 = {0.f, 0.f, 0.f, 0.f};
    f4v a2 = {0.f, 0.f, 0.f, 0.f};
    f4v a3 = {0.f, 0.f, 0.f, 0.f};

    int f = f0 + row;
    const f4v* p = xp + (size_t)f * 32;
    for (; f + 56 < f1; f += 64, p += 2048) {
        f4v v0 = __builtin_nontemporal_load(p);
        f4v v1 = __builtin_nontemporal_load(p + 256);
        f4v v2 = __builtin_nontemporal_load(p + 512);
        f4v v3 = __builtin_nontemporal_load(p + 768);
        f4v v4 = __builtin_nontemporal_load(p + 1024);
        f4v v5 = __builtin_nontemporal_load(p + 1280);
        f4v v6 = __builtin_nontemporal_load(p + 1536);
        f4v v7 = __builtin_nontemporal_load(p + 1792);
        float p0 = dot4(v0, g), p1 = dot4(v1, g),
              p2 = dot4(v2, g), p3 = dot4(v3, g),
              p4 = dot4(v4, g), p5 = dot4(v5, g),
              p6 = dot4(v6, g), p7 = dot4(v7, g);
#pragma unroll
        for (int m = 16; m >= 1; m >>= 1) {
            p0 += __shfl_xor(p0, m, 64);
            p1 += __shfl_xor(p1, m, 64);
            p2 += __shfl_xor(p2, m, 64);
            p3 += __shfl_xor(p3, m, 64);
            p4 += __shfl_xor(p4, m, 64);
            p5 += __shfl_xor(p5, m, 64);
            p6 += __shfl_xor(p6, m, 64);
            p7 += __shfl_xor(p7, m, 64);
        }
        float g0 = 1.0f / (1.0f + __expf(-p0));
        float g1 = 1.0f / (1.0f + __expf(-p1));
        float g2 = 1.0f / (1.0f + __expf(-p2));
        float g3 = 1.0f / (1.0f + __expf(-p3));
        float g4 = 1.0f / (1.0f + __expf(-p4));
        float g5 = 1.0f / (1.0f + __expf(-p5));
        float g6 = 1.0f / (1.0f + __expf(-p6));
        float g7 = 1.0f / (1.0f + __expf(-p7));
        a0 += g0 * v0 + g4 * v4;
        a1 += g1 * v1 + g5 * v5;
        a2 += g2 * v2 + g6 * v6;
        a3 += g3 * v3 + g7 * v7;
    }
    for (; f < f1; f += 8, p += 256) {
        f4v v = __builtin_nontemporal_load(p);
        float pp = dot4(v, g);
#pragma unroll
        for (int m = 16; m >= 1; m >>= 1) pp += __shfl_xor(pp, m, 64);
        float gg = 1.0f / (1.0f + __expf(-pp));
        a0 += gg * v;
    }
    a0 += a1; a2 += a3; a0 += a2;

    __shared__ f4v s[256];
    s[tid] = a0;
    __syncthreads();
#pragma unroll
    for (int stride = 128; stride >= 32; stride >>= 1) {
        if (tid < stride) {
            f4v m = s[tid] + s[tid + stride];
            s[tid] = m;
        }
        __syncthreads();
    }
    if (tid < 32) {
        float inv = 1.0f / fmaxf((float)(f1 - f0), 1.0f);
        f4v m = s[tid];
        ((f4v*)(out + ((size_t)j * B + b) * 128))[tid] = m * inv;
    }
}

extern "C" void kernel_launch(void* const* d_in, const int* in_sizes, int n_in,
                              void* d_out, int out_size, void* d_ws, size_t ws_size,
                              hipStream_t stream) {
    const float* x  = (const float*)d_in[0];
    const int* idx  = (const int*)d_in[1];
    const float* W  = (const float*)d_in[3];
    float* out      = (float*)d_out;

    const int F = in_sizes[1];
    int C = 1;
    while ((long long)C * C < (long long)in_sizes[3]) ++C;   // 128
    const int J = in_sizes[0] / (F * C);                     // 25
    const int B = out_size / (J * C);                        // 128

    char* ws = (char*)d_ws;
    int* seg = (int*)ws;
    size_t off = (((size_t)(B + 1) * sizeof(int)) + 255) & ~(size_t)255;
    float* gcb = (float*)(ws + off);

    seg_bounds_kernel<<<(B + 1 + 255) / 256, 256, 0, stream>>>(idx, F, B, seg);
    mean_gc_kernel<<<J * B, 256, 0, stream>>>(x, seg, W, F, B, gcb);
    gate_scatter_kernel<<<J * B, 256, 0, stream>>>(x, gcb, seg, F, B, out);
}